// Round 6
// baseline (266.971 us; speedup 1.0000x reference)
//
#include <hip/hip_runtime.h>
#include <math.h>
#include <stdint.h>

#define BB 8
#define NN 16384
#define CC 80
#define TT 100
#define CAP 1024
#define BAND_LO 0.97f
#define LCAP 64            // per-slice per-class list cap
#define SLICES 32          // slices per batch (512 rows each)
#define ROWS 512

typedef unsigned int u32;
typedef unsigned long long u64;

// ---------- K1: coalesced one-pass band gather, atomic-free global output ----------
// block = (b, slice); scans slice row-major (coalesced float4), buckets hits into
// per-class LDS lists, writes raw counts + segments to its own global region.
__global__ __launch_bounds__(256) void gather_kernel(const float* __restrict__ scores,
                                                     u64* __restrict__ cand,
                                                     int* __restrict__ cnts) {
  __shared__ u64 lkeys[CC * LCAP];   // 40 KB
  __shared__ int lcnt[CC];

  int b = blockIdx.x / SLICES;
  int slice = blockIdx.x % SLICES;
  int n0 = slice * ROWS;
  int tid = threadIdx.x;

  if (tid < CC) lcnt[tid] = 0;
  __syncthreads();

  const float4* s4 = (const float4*)scores;
  size_t base4 = ((size_t)b * NN + n0) * (CC / 4);
  for (int i = tid; i < ROWS * (CC / 4); i += 256) {
    float4 q = s4[base4 + i];
    int ib = i * 4;
    float vv[4] = {q.x, q.y, q.z, q.w};
#pragma unroll
    for (int e = 0; e < 4; ++e) {
      float v = vv[e];
      if (v >= BAND_LO) {
        int fe = ib + e;
        int c = fe % CC;
        int n = n0 + fe / CC;
        int s = atomicAdd(&lcnt[c], 1);          // LDS atomic, low contention
        if (s < LCAP) lkeys[c * LCAP + s] = ((u64)__float_as_uint(v) << 32) | (u32)(~(u32)n);
      }
    }
  }
  __syncthreads();

  // raw counts (may exceed LCAP -> overflow signal for K2)
  if (tid < CC) cnts[((size_t)(b * CC + tid)) * SLICES + slice] = lcnt[tid];
  // coalesced segment write-out
  for (int idx = tid; idx < CC * LCAP; idx += 256) {
    int c = idx >> 6, i = idx & (LCAP - 1);
    int lc = lcnt[c]; if (lc > LCAP) lc = LCAP;
    if (i < lc) cand[(((size_t)(b * CC + c)) * SLICES + slice) * LCAP + i] = lkeys[idx];
  }
}

// ---------- K2: per-(b,c) single-wave sort + chunked-bitmask greedy ----------
__global__ __launch_bounds__(64) void nms_kernel(const float* __restrict__ boxes,
                                                 const float* __restrict__ scores,
                                                 const u64* __restrict__ cand,
                                                 const int* __restrict__ cnts,
                                                 float* __restrict__ det_score,
                                                 float* __restrict__ det_box) {
  __shared__ u64 keys[CAP];        // 8 KB
  __shared__ float4 cbx[64];       // current chunk boxes
  __shared__ float carea[64];
  __shared__ float4 abx[TT];       // accepted boxes
  __shared__ float aarea[TT];
  __shared__ int cnt_s;

  int bc = blockIdx.x;
  int b = bc / CC, c = bc % CC;
  int lane = threadIdx.x;
  const float* bsrc = boxes + (size_t)b * NN * 4;
  float* dsc = det_score + (size_t)bc * TT;
  float4* dbx = (float4*)det_box + (size_t)bc * TT;

  // ---- concatenate 32 gather segments (wave prefix-sum, no atomics)
  int craw = (lane < SLICES) ? cnts[(size_t)bc * SLICES + lane] : 0;
  bool ok = __all(craw <= LCAP);
  int x = (craw > LCAP) ? LCAP : craw;
  int incl = x;
#pragma unroll
  for (int d = 1; d < 64; d <<= 1) {
    int y = __shfl_up(incl, d);
    if (lane >= d) incl += y;
  }
  int off = incl - x;
  int m_total = __shfl(incl, 63);
  bool pre_ok = ok && (m_total <= CAP);
  if (pre_ok && lane < SLICES) {
    const u64* seg = cand + ((size_t)bc * SLICES + lane) * LCAP;
    for (int i = 0; i < x; ++i) keys[off + i] = seg[i];
  }
  __builtin_amdgcn_wave_barrier();

  int nacc = 0;
  float lo = BAND_LO, hi = INFINITY;
  bool first = true;

  for (;;) {
    // ---- candidate list for band [lo, hi)
    int m;
    if (first && pre_ok) {
      m = m_total;
    } else {
      float band_lo = lo;
      for (int tries = 0;; ++tries) {
        if (lane == 0) cnt_s = 0;
        __builtin_amdgcn_wave_barrier();
        for (int n = lane; n < NN; n += 64) {
          float v = scores[((size_t)b * NN + n) * CC + c];
          if (v > 0.3f && v >= band_lo && v < hi) {
            int s = atomicAdd(&cnt_s, 1);
            if (s < CAP) keys[s] = ((u64)__float_as_uint(v) << 32) | (u32)(~(u32)n);
          }
        }
        __builtin_amdgcn_wave_barrier();
        if (cnt_s <= CAP || tries >= 24) break;
        float hi_eff = (hi > 1.0f) ? 1.0f : hi;
        band_lo = 0.5f * (band_lo + hi_eff);
        __builtin_amdgcn_wave_barrier();
      }
      m = (cnt_s < CAP) ? cnt_s : CAP;
      lo = band_lo;                   // consumed band is [band_lo, hi)
    }
    first = false;

    if (m > 0) {
      // pad to power of two
      int n2 = 64;
      while (n2 < m) n2 <<= 1;
      for (int s = m + lane; s < n2; s += 64) keys[s] = 0ull;
      __builtin_amdgcn_wave_barrier();
      // single-wave bitonic sort descending (score desc, idx asc via ~idx)
      for (int k = 2; k <= n2; k <<= 1) {
        for (int j = k >> 1; j > 0; j >>= 1) {
          for (int i = lane; i < n2; i += 64) {
            int ixj = i ^ j;
            if (ixj > i) {
              u64 a = keys[i], d2 = keys[ixj];
              bool up = ((i & k) == 0);
              if (up ? (a < d2) : (a > d2)) { keys[i] = d2; keys[ixj] = a; }
            }
          }
          __builtin_amdgcn_wave_barrier();
        }
      }

      // ---- chunked-bitmask greedy (exactly mirrors serial greedy order)
      int nchunks = (m + 63) >> 6;
      for (int ch = 0; ch < nchunks && nacc < TT; ++ch) {
        int s = ch * 64 + lane;
        bool have = s < m;
        u64 key = have ? keys[s] : 0ull;
        float v = __uint_as_float((u32)(key >> 32));
        float4 bx = make_float4(0.f, 0.f, 0.f, 0.f);
        if (have) {
          u32 gi = ~(u32)key;
          bx = *(const float4*)(bsrc + (size_t)gi * 4);
        }
        float area = fmaxf(bx.z - bx.x, 0.f) * fmaxf(bx.w - bx.y, 0.f);
        cbx[lane] = bx; carea[lane] = area;
        __builtin_amdgcn_wave_barrier();

        // vs accepted set (lane-parallel, broadcast LDS reads)
        bool dead0 = !have;
        for (int j = 0; j < nacc; ++j) {
          float4 a = abx[j]; float aj = aarea[j];
          float yy1 = fmaxf(a.x, bx.x), xx1 = fmaxf(a.y, bx.y);
          float yy2 = fminf(a.z, bx.z), xx2 = fminf(a.w, bx.w);
          float inter = fmaxf(yy2 - yy1, 0.f) * fmaxf(xx2 - xx1, 0.f);
          float uni = aj + area - inter;
          if (inter / fmaxf(uni, 1e-9f) >= 0.5f) dead0 = true;
        }
        // intra-chunk overlap mask: bit j => candidate j (if accepted) suppresses me
        u64 mymask = 0ull;
        for (int j = 0; j < 64; ++j) {
          float4 a = cbx[j]; float aj = carea[j];
          float yy1 = fmaxf(a.x, bx.x), xx1 = fmaxf(a.y, bx.y);
          float yy2 = fminf(a.z, bx.z), xx2 = fminf(a.w, bx.w);
          float inter = fmaxf(yy2 - yy1, 0.f) * fmaxf(xx2 - xx1, 0.f);
          float uni = aj + area - inter;
          bool ov = (j < lane) && (inter / fmaxf(uni, 1e-9f) >= 0.5f);
          if (ov) mymask |= (1ull << j);
        }
        // serial-in-scalar resolution
        u64 deadm = __ballot(dead0);
        u64 accb = 0ull;
        int space = TT - nacc;
        for (int j = 0; j < 64; ++j) {
          if (!((deadm >> j) & 1ull)) {
            accb |= 1ull << j;
            if ((int)__popcll(accb) >= space) break;
            deadm |= __ballot((mymask >> j) & 1ull);
          }
        }
        int rank = __popcll(accb & ((1ull << lane) - 1ull));
        bool accme = ((accb >> lane) & 1ull) && (nacc + rank < TT);
        if (accme) {
          int slot = nacc + rank;
          abx[slot] = bx; aarea[slot] = area;
          dsc[slot] = v;
          dbx[slot] = bx;
        }
        __builtin_amdgcn_wave_barrier();
        nacc += (int)__popcll(accb);
        if (nacc > TT) nacc = TT;
      }
    }

    if (nacc >= TT || lo <= 0.0f) break;
    hi = lo;
    float nlo = lo - 0.03f;
    lo = (nlo <= 0.31f) ? 0.0f : nlo;
  }
  // sentinel for empty slots
  for (int t = nacc + lane; t < TT; t += 64) dsc[t] = -INFINITY;
}

// ---------- K3: per-batch top-100 via threshold-select + small sort ----------
__device__ __forceinline__ void bitonic_desc(u64* buf, int n2, int tid) {
  for (int k = 2; k <= n2; k <<= 1) {
    for (int j = k >> 1; j > 0; j >>= 1) {
      for (int i = tid; i < n2; i += 256) {
        int ixj = i ^ j;
        if (ixj > i) {
          u64 a = buf[i], d2 = buf[ixj];
          bool up = ((i & k) == 0);
          if (up ? (a < d2) : (a > d2)) { buf[i] = d2; buf[ixj] = a; }
        }
      }
      __syncthreads();
    }
  }
}

__global__ __launch_bounds__(256) void topk_select(const float* __restrict__ det_score,
                                                   const float* __restrict__ det_box,
                                                   float* __restrict__ out) {
  __shared__ u64 kk[CC * TT];     // 64 KB
  __shared__ u64 buf[8192];       // 64 KB
  __shared__ int scnt[CC];
  __shared__ int total_s, base_s, vc_s;

  int b = blockIdx.x, tid = threadIdx.x;
  for (int i = tid; i < CC * TT; i += 256) {
    float v = det_score[(size_t)b * CC * TT + i];
    kk[i] = (v == -INFINITY) ? 0ull : (((u64)__float_as_uint(v) << 32) | (u32)(~(u32)i));
  }
  if (tid == 0) { total_s = 0; base_s = 0; vc_s = 0; }
  __syncthreads();

  // threshold from per-class top-2 (subset => t <= t100 => superset gathered)
  for (int i = tid; i < 256; i += 256) buf[i] = (i < 2 * CC) ? kk[(i >> 1) * TT + (i & 1)] : 0ull;
  __syncthreads();
  bitonic_desc(buf, 256, tid);
  u64 t = buf[99];
  u64 tq = t ? t : 1ull;
  __syncthreads();

  if (tid < CC) {
    int lo2 = 0, hi2 = TT;
    while (lo2 < hi2) {
      int mid = (lo2 + hi2) >> 1;
      if (kk[tid * TT + mid] >= tq) lo2 = mid + 1; else hi2 = mid;
    }
    scnt[tid] = lo2;
    atomicAdd(&total_s, lo2);
  }
  __syncthreads();
  int total = total_s;
  int n2 = 128;
  while (n2 < total) n2 <<= 1;

  if (tid < CC) {
    int m = scnt[tid];
    int gb = atomicAdd(&base_s, m);
    for (int i = 0; i < m; ++i) buf[gb + i] = kk[tid * TT + i];
  }
  __syncthreads();
  for (int i = total + tid; i < n2; i += 256) buf[i] = 0ull;
  __syncthreads();
  bitonic_desc(buf, n2, tid);

  float* ob = out + (size_t)b * TT * 4;            // [0,3200)
  float* os = out + BB * TT * 4 + (size_t)b * TT;  // [3200,4000)
  float* ol = out + BB * TT * 5 + (size_t)b * TT;  // [4000,4800)
  if (tid < TT) {
    u64 k = buf[tid];
    bool valid = (k != 0ull);
    u32 j = valid ? (u32)(~(u32)k) : 0u;
    float v = __uint_as_float((u32)(k >> 32));
    float4 bx = make_float4(0.f, 0.f, 0.f, 0.f);
    if (valid) bx = *(const float4*)(det_box + ((size_t)b * CC * TT + j) * 4);
    ((float4*)ob)[tid] = bx;
    os[tid] = valid ? v : 0.0f;
    ol[tid] = valid ? (float)(j / TT) : 0.0f;
    if (valid) atomicAdd(&vc_s, 1);
  }
  __syncthreads();
  if (tid == 0) out[BB * TT * 5 + BB * TT + b] = (float)vc_s;
}

// ---------- launch ----------
extern "C" void kernel_launch(void* const* d_in, const int* in_sizes, int n_in,
                              void* d_out, int out_size, void* d_ws, size_t ws_size,
                              hipStream_t stream) {
  const float* boxes  = (const float*)d_in[0];   // (8,16384,4)
  const float* scores = (const float*)d_in[1];   // (8,16384,80)
  float* out = (float*)d_out;                    // 4808 floats

  char* ws = (char*)d_ws;
  u64*   cand      = (u64*)ws;                        // 640*32*64*8 = 10,485,760
  int*   cnts      = (int*)(ws + 10485760);           // 640*32*4    =     81,920
  float* det_box   = (float*)(ws + 10485760 + 81920); // 640*100*16  =  1,024,000
  float* det_score = (float*)(ws + 10485760 + 81920 + 1024000); // 640*100*4 = 256,000

  gather_kernel<<<BB * SLICES, 256, 0, stream>>>(scores, cand, cnts);
  nms_kernel<<<BB * CC, 64, 0, stream>>>(boxes, scores, cand, cnts, det_score, det_box);
  topk_select<<<BB, 256, 0, stream>>>(det_score, det_box, out);
}

// Round 7
// 154.734 us; speedup vs baseline: 1.7254x; 1.7254x over previous
//
#include <hip/hip_runtime.h>
#include <math.h>
#include <stdint.h>

#define BB 8
#define NN 16384
#define CC 80
#define TT 100
#define CAP 1024
#define BAND_LO 0.984375f        // 1 - 1/64
#define BASEBITS 0x3F7C0000u     // __float_as_uint(0.984375f)
#define LCAP 24                  // per-slice per-class cap (E=4, P(>24)~1e-13)
#define SLICES 64
#define ROWS 256                 // NN / SLICES

typedef unsigned int u32;
typedef unsigned long long u64;

// ---------- bitonic sorts (descending), 256 threads ----------
__device__ __forceinline__ void bitonic_desc32(u32* buf, int n2, int tid) {
  for (int k = 2; k <= n2; k <<= 1)
    for (int j = k >> 1; j > 0; j >>= 1) {
      for (int i = tid; i < n2; i += 256) {
        int ixj = i ^ j;
        if (ixj > i) {
          u32 a = buf[i], d2 = buf[ixj];
          bool up = ((i & k) == 0);
          if (up ? (a < d2) : (a > d2)) { buf[i] = d2; buf[ixj] = a; }
        }
      }
      __syncthreads();
    }
}
__device__ __forceinline__ void bitonic_desc64(u64* buf, int n2, int tid) {
  for (int k = 2; k <= n2; k <<= 1)
    for (int j = k >> 1; j > 0; j >>= 1) {
      for (int i = tid; i < n2; i += 256) {
        int ixj = i ^ j;
        if (ixj > i) {
          u64 a = buf[i], d2 = buf[ixj];
          bool up = ((i & k) == 0);
          if (up ? (a < d2) : (a > d2)) { buf[i] = d2; buf[ixj] = a; }
        }
      }
      __syncthreads();
    }
}

// ---------- K1: coalesced one-pass band gather, atomic-free global output ----------
__global__ __launch_bounds__(256) void gather_kernel(const float* __restrict__ scores,
                                                     u32* __restrict__ cand,
                                                     int* __restrict__ cnts) {
  __shared__ u32 lkeys[CC * LCAP];   // 7.7 KB
  __shared__ int lcnt[CC];

  int b = blockIdx.x / SLICES;
  int slice = blockIdx.x % SLICES;
  int n0 = slice * ROWS;
  int tid = threadIdx.x;

  if (tid < CC) lcnt[tid] = 0;
  __syncthreads();

  const float4* s4 = (const float4*)scores;
  size_t base4 = ((size_t)b * NN + n0) * (CC / 4);
  for (int i = tid; i < ROWS * (CC / 4); i += 256) {
    float4 q = s4[base4 + i];
    int ib = i * 4;
    float vv[4] = {q.x, q.y, q.z, q.w};
#pragma unroll
    for (int e = 0; e < 4; ++e) {
      float v = vv[e];
      if (v >= BAND_LO) {
        int fe = ib + e;
        int c = fe % CC;
        int n = n0 + fe / CC;
        int s = atomicAdd(&lcnt[c], 1);          // LDS atomic, sparse hits
        if (s < LCAP)
          lkeys[c * LCAP + s] = ((__float_as_uint(v) - BASEBITS) << 14) | (u32)(16383 - n);
      }
    }
  }
  __syncthreads();

  int bc0 = b * CC;
  if (tid < CC) cnts[(size_t)(bc0 + tid) * SLICES + slice] = lcnt[tid];  // raw count
  for (int idx = tid; idx < CC * LCAP; idx += 256) {
    int c = idx / LCAP, i = idx % LCAP;
    int lc = lcnt[c]; if (lc > LCAP) lc = LCAP;
    if (i < lc) cand[((size_t)(bc0 + c) * SLICES + slice) * LCAP + i] = lkeys[idx];
  }
}

// ---------- K2: per-(b,c) sort + pair-parallel bitmask greedy (256 threads) ----------
__global__ __launch_bounds__(256) void nms_kernel(const float* __restrict__ boxes,
                                                  const float* __restrict__ scores,
                                                  const u32* __restrict__ cand,
                                                  const int* __restrict__ cnts,
                                                  float* __restrict__ det_score,
                                                  float* __restrict__ det_box) {
  __shared__ u64 keys[CAP];          // 8 KB (fallback); (u32*)keys = fast-path buffer
  __shared__ float sv[CAP];          // 4 KB sorted scores
  __shared__ float4 bxs[CAP];        // 16 KB sorted boxes
  __shared__ float4 abx[TT];         // accepted boxes
  __shared__ float aarea[TT];
  __shared__ u32 killp[4][64];       // kill-matrix 16-bit slices
  __shared__ int partial[256];       // accepted-suppression partials
  __shared__ int off_s[SLICES], x_s[SLICES];
  __shared__ int mtot_s, ok_s, nacc_s, cnt_s;

  int bc = blockIdx.x;
  int b = bc / CC, c = bc % CC;
  int tid = threadIdx.x;
  const float* bsrc = boxes + (size_t)b * NN * 4;
  float* dsc = det_score + (size_t)bc * TT;
  float4* dbx = (float4*)det_box + (size_t)bc * TT;
  u32* k32 = (u32*)keys;

  // ---- concat offsets (wave 0 prefix-scan, no atomics)
  if (tid < 64) {
    int craw = cnts[(size_t)bc * SLICES + tid];
    int okl = (craw <= LCAP) ? 1 : 0;
    bool ok = __all(okl);
    int x = (craw > LCAP) ? LCAP : craw;
    int incl = x;
#pragma unroll
    for (int d = 1; d < 64; d <<= 1) {
      int y = __shfl_up(incl, d);
      if (tid >= d) incl += y;
    }
    off_s[tid] = incl - x; x_s[tid] = x;
    if (tid == 63) mtot_s = incl;
    if (tid == 0) { ok_s = ok ? 1 : 0; nacc_s = 0; }
  }
  __syncthreads();
  int m_total = mtot_s;
  bool pre_ok = ok_s && (m_total <= CAP);
  if (pre_ok) {
    int slice = tid >> 2, li = tid & 3;
    int x = x_s[slice], off = off_s[slice];
    const u32* seg = cand + ((size_t)bc * SLICES + slice) * LCAP;
    for (int i = li; i < x; i += 4) k32[off + i] = seg[i];
  }
  __syncthreads();

  float lo = BAND_LO, hi = INFINITY;
  bool first = true;
  int nacc = 0;

  for (;;) {
    // ---- build sorted candidate arrays sv/bxs for this band
    int m;
    bool fast = first && pre_ok;
    if (fast) {
      m = m_total;
      if (m > 0) {
        int n2 = 64; while (n2 < m) n2 <<= 1;
        for (int s = m + tid; s < n2; s += 256) k32[s] = 0u;
        __syncthreads();
        bitonic_desc32(k32, n2, tid);
        for (int s = tid; s < m; s += 256) {
          u32 k = k32[s];
          sv[s] = __uint_as_float(BASEBITS + (k >> 14));
          u32 n = 16383u - (k & 16383u);
          bxs[s] = *(const float4*)(bsrc + (size_t)n * 4);
        }
        __syncthreads();
      }
    } else {
      float band_lo = lo;
      for (int tries = 0;; ++tries) {
        if (tid == 0) cnt_s = 0;
        __syncthreads();
        for (int n = tid; n < NN; n += 256) {
          float v = scores[((size_t)b * NN + n) * CC + c];
          if (v > 0.3f && v >= band_lo && v < hi) {
            int s = atomicAdd(&cnt_s, 1);
            if (s < CAP) keys[s] = ((u64)__float_as_uint(v) << 32) | (u32)(~(u32)n);
          }
        }
        __syncthreads();
        if (cnt_s <= CAP || tries >= 24) break;
        float hi_eff = (hi > 1.0f) ? 1.0f : hi;
        band_lo = 0.5f * (band_lo + hi_eff);
        __syncthreads();
      }
      m = (cnt_s < CAP) ? cnt_s : CAP;
      lo = band_lo;                   // consumed band = [band_lo, hi)
      if (m > 0) {
        int n2 = 64; while (n2 < m) n2 <<= 1;
        for (int s = m + tid; s < n2; s += 256) keys[s] = 0ull;
        __syncthreads();
        bitonic_desc64(keys, n2, tid);
        for (int s = tid; s < m; s += 256) {
          u64 k = keys[s];
          sv[s] = __uint_as_float((u32)(k >> 32));
          u32 n = ~(u32)k;
          bxs[s] = *(const float4*)(bsrc + (size_t)n * 4);
        }
        __syncthreads();
      }
    }
    first = false;

    // ---- pair-parallel chunked greedy (exactly mirrors serial order)
    if (m > 0) {
      int nchunks = (m + 63) >> 6;
      int j = tid & 63, blk = tid >> 6;
      for (int ch = 0; ch < nchunks; ++ch) {
        int na = nacc_s;
        if (na >= TT) break;
        int sj = ch * 64 + j;
        bool have = sj < m;
        float4 bj = have ? bxs[sj] : make_float4(0.f, 0.f, 0.f, 0.f);
        float aj = fmaxf(bj.z - bj.x, 0.f) * fmaxf(bj.w - bj.y, 0.f);

        // suppression vs accepted set, 4-way split over blk
        int dead = have ? 0 : 1;
        for (int a = blk; a < na; a += 4) {
          float4 ab = abx[a]; float aa = aarea[a];
          float yy1 = fmaxf(ab.x, bj.x), xx1 = fmaxf(ab.y, bj.y);
          float yy2 = fminf(ab.z, bj.z), xx2 = fminf(ab.w, bj.w);
          float inter = fmaxf(yy2 - yy1, 0.f) * fmaxf(xx2 - xx1, 0.f);
          float uni = aa + aj - inter;
          if (inter / fmaxf(uni, 1e-9f) >= 0.5f) dead = 1;
        }
        partial[tid] = dead;

        // kill matrix: j kills i (i > j), 16 victims per thread
        u32 kp = 0;
#pragma unroll
        for (int r = 0; r < 16; ++r) {
          int i = blk * 16 + r;
          float4 bi = bxs[ch * 64 + i];
          float ai = fmaxf(bi.z - bi.x, 0.f) * fmaxf(bi.w - bi.y, 0.f);
          float yy1 = fmaxf(bj.x, bi.x), xx1 = fmaxf(bj.y, bi.y);
          float yy2 = fminf(bj.z, bi.z), xx2 = fminf(bj.w, bi.w);
          float inter = fmaxf(yy2 - yy1, 0.f) * fmaxf(xx2 - xx1, 0.f);
          float uni = aj + ai - inter;
          if (i > j && (inter / fmaxf(uni, 1e-9f) >= 0.5f)) kp |= (1u << r);
        }
        killp[blk][j] = kp;
        __syncthreads();

        // wave-0 resolution
        if (tid < 64) {
          int l = tid;
          int d0 = partial[l] | partial[64 + l] | partial[128 + l] | partial[192 + l];
          u32 klo = killp[0][l] | (killp[1][l] << 16);
          u32 khi = killp[2][l] | (killp[3][l] << 16);
          u64 deadm = __ballot(d0 != 0);
          u64 accb = 0ull;
          int space = TT - na;
          for (int jj = 0; jj < 64; ++jj) {
            if (!((deadm >> jj) & 1ull)) {
              accb |= (1ull << jj);
              if ((int)__popcll(accb) >= space) break;
              u64 kj = ((u64)(u32)__shfl((int)klo, jj)) |
                       (((u64)(u32)__shfl((int)khi, jj)) << 32);
              deadm |= kj;
            }
          }
          bool accme = ((accb >> l) & 1ull) != 0;
          if (accme) {
            int rank = __popcll(accb & ((1ull << l) - 1ull));
            int slot = na + rank;
            abx[slot] = bj; aarea[slot] = aj;
            dsc[slot] = sv[ch * 64 + l];
            dbx[slot] = bj;
          }
          if (l == 0) nacc_s = na + (int)__popcll(accb);
        }
        __syncthreads();
      }
    }

    nacc = nacc_s;
    if (nacc >= TT || lo <= 0.0f) break;
    hi = lo;
    float nlo = lo - 0.03f;
    lo = (nlo <= 0.31f) ? 0.0f : nlo;
    __syncthreads();
  }
  // sentinels
  for (int t = nacc + tid; t < TT; t += 256) dsc[t] = -INFINITY;
}

// ---------- K3: per-batch top-100 via threshold-select + small sort ----------
__global__ __launch_bounds__(256) void topk_select(const float* __restrict__ det_score,
                                                   const float* __restrict__ det_box,
                                                   float* __restrict__ out) {
  __shared__ u64 kk[CC * TT];     // 64 KB
  __shared__ u64 buf[8192];       // 64 KB
  __shared__ int scnt[CC];
  __shared__ int total_s, base_s, vc_s;

  int b = blockIdx.x, tid = threadIdx.x;
  for (int i = tid; i < CC * TT; i += 256) {
    float v = det_score[(size_t)b * CC * TT + i];
    kk[i] = (v == -INFINITY) ? 0ull : (((u64)__float_as_uint(v) << 32) | (u32)(~(u32)i));
  }
  if (tid == 0) { total_s = 0; base_s = 0; vc_s = 0; }
  __syncthreads();

  for (int i = tid; i < 256; i += 256) buf[i] = (i < 2 * CC) ? kk[(i >> 1) * TT + (i & 1)] : 0ull;
  __syncthreads();
  bitonic_desc64(buf, 256, tid);
  u64 t = buf[99];
  u64 tq = t ? t : 1ull;
  __syncthreads();

  if (tid < CC) {
    int lo2 = 0, hi2 = TT;
    while (lo2 < hi2) {
      int mid = (lo2 + hi2) >> 1;
      if (kk[tid * TT + mid] >= tq) lo2 = mid + 1; else hi2 = mid;
    }
    scnt[tid] = lo2;
    atomicAdd(&total_s, lo2);
  }
  __syncthreads();
  int total = total_s;
  int n2 = 128;
  while (n2 < total) n2 <<= 1;

  if (tid < CC) {
    int m = scnt[tid];
    int gb = atomicAdd(&base_s, m);
    for (int i = 0; i < m; ++i) buf[gb + i] = kk[tid * TT + i];
  }
  __syncthreads();
  for (int i = total + tid; i < n2; i += 256) buf[i] = 0ull;
  __syncthreads();
  bitonic_desc64(buf, n2, tid);

  float* ob = out + (size_t)b * TT * 4;            // [0,3200)
  float* os = out + BB * TT * 4 + (size_t)b * TT;  // [3200,4000)
  float* ol = out + BB * TT * 5 + (size_t)b * TT;  // [4000,4800)
  if (tid < TT) {
    u64 k = buf[tid];
    bool valid = (k != 0ull);
    u32 j = valid ? (u32)(~(u32)k) : 0u;
    float v = __uint_as_float((u32)(k >> 32));
    float4 bx = make_float4(0.f, 0.f, 0.f, 0.f);
    if (valid) bx = *(const float4*)(det_box + ((size_t)b * CC * TT + j) * 4);
    ((float4*)ob)[tid] = bx;
    os[tid] = valid ? v : 0.0f;
    ol[tid] = valid ? (float)(j / TT) : 0.0f;
    if (valid) atomicAdd(&vc_s, 1);
  }
  __syncthreads();
  if (tid == 0) out[BB * TT * 5 + BB * TT + b] = (float)vc_s;
}

// ---------- launch ----------
extern "C" void kernel_launch(void* const* d_in, const int* in_sizes, int n_in,
                              void* d_out, int out_size, void* d_ws, size_t ws_size,
                              hipStream_t stream) {
  const float* boxes  = (const float*)d_in[0];   // (8,16384,4)
  const float* scores = (const float*)d_in[1];   // (8,16384,80)
  float* out = (float*)d_out;                    // 4808 floats

  char* ws = (char*)d_ws;
  const size_t CAND_B = (size_t)BB * CC * SLICES * LCAP * 4;  // 3,932,160
  const size_t CNTS_B = (size_t)BB * CC * SLICES * 4;         //   163,840
  const size_t DBX_B  = (size_t)BB * CC * TT * 16;            // 1,024,000
  u32*   cand      = (u32*)ws;
  int*   cnts      = (int*)(ws + CAND_B);
  float* det_box   = (float*)(ws + CAND_B + CNTS_B);
  float* det_score = (float*)(ws + CAND_B + CNTS_B + DBX_B);

  gather_kernel<<<BB * SLICES, 256, 0, stream>>>(scores, cand, cnts);
  nms_kernel<<<BB * CC, 256, 0, stream>>>(boxes, scores, cand, cnts, det_score, det_box);
  topk_select<<<BB, 256, 0, stream>>>(det_score, det_box, out);
}